// Round 4
// baseline (610.281 us; speedup 1.0000x reference)
//
#include <hip/hip_runtime.h>
#include <hip/hip_bf16.h>

// Fused masked SDPA: B=64, LQ=LK=1024, D=64, temperature=8.
// R7: maximize per-wave memory-level parallelism. Counter math from R6:
// ~105K cy/block vs ~6K cy of issue work => 95% memory stall; aggregate BW
// (1.7 TB/s, 22% peak) = waves x bytes-in-flight / latency, so the cap is
// outstanding bytes per wave, not work.
//  - Mask pipeline depth 8 (40 dword loads in flight vs 10 before). Row max
//    is computed WITHOUT masks (exact: any shift >= true max works; s is
//    bounded so no underflow), so arriving mask tiles are bit-packed
//    (km && ms -> 4 bits/tile, 16 tiles in 2 regs) and consumed only at the
//    exp stage: e = bit ? exp(s-m) : 0. Frees the VGPRs depth-8 would cost.
//  - K prefetch depth 2 (ping-pong), fully unrolled, static indexing.
//  - P global stores moved OUT of the pass-2 loop into an epilogue burst:
//    in-loop they sat ahead of V loads in the in-order vmcnt queue, so every
//    V wait also waited on store retirement. Epilogue = 64 independent
//    stores, max MLP, pass-2 chain is pure V-load -> LDS -> MFMA.
//  - Everything else: proven R6 structure (private-LDS V transpose, P LDS
//    transpose, one exp pass, hw cvt, Q prescaled 1/8, plain stores).

#define NB   64
#define SLQ  1024
#define SLK  1024
#define DH   64
#define TQ   16
#define TK   64
#define NKT  16
#define MD   8    // mask pipeline depth (tiles)
#define VSTR 76   // V slice row stride (u16): 152B -> column reads 2-way max
#define PSTR 40   // P slice row stride (u16): 80B, 16B-aligned for b128
#define OSTR 68   // O partial row stride (f32)

typedef __attribute__((ext_vector_type(4))) float          f32x4;
typedef __attribute__((ext_vector_type(8))) __bf16         bf16x8;
typedef __attribute__((ext_vector_type(8))) unsigned short u16x8;
typedef __attribute__((ext_vector_type(4))) unsigned short u16x4;

static __device__ __forceinline__ unsigned short f2bf(float f) {
  return __builtin_bit_cast(unsigned short, (__bf16)f);   // hw cvt, RTNE
}
static __device__ __forceinline__ bf16x8 cvt8(f32x4 a, f32x4 b) {
  bf16x8 r;
#pragma unroll
  for (int i = 0; i < 4; ++i) { r[i] = (__bf16)a[i]; r[i + 4] = (__bf16)b[i]; }
  return r;
}
static __device__ __forceinline__ u16x4 cvt4(f32x4 v) {
  u16x4 h;
#pragma unroll
  for (int i = 0; i < 4; ++i) h[i] = f2bf(v[i]);
  return h;
}

__global__ __launch_bounds__(256, 3) void sdpa_fused(
    const float* __restrict__ Q, const float* __restrict__ K,
    const float* __restrict__ V, const int* __restrict__ QM,
    const int* __restrict__ KM, const int* __restrict__ MSK,
    float* __restrict__ OUT_AV, float* __restrict__ OUT_P) {
  // XCD swizzle: co-schedule same-batch blocks on one XCD for K/V L2 reuse
  const int g    = blockIdx.x;
  const int slot = g >> 3;
  const int b    = ((slot >> 6) << 3) | (g & 7);
  const int q0   = (slot & 63) * TQ;

  const int tid  = threadIdx.x;
  const int wave = tid >> 6;
  const int lane = tid & 63;
  const int col  = lane & 15;
  const int quad = lane >> 4;
  const int lrow = quad;             // staging row subgroup
  const int lc4  = col * 4;          // staging column (x4 elements)

  // LDS: [0,19456): per-wave union of V slice (4864 B) / O partial (4352 B)
  //      [19456,24576): per-wave P slice (1280 B)
  //      [24576,25216): softmax stats
  __shared__ __align__(16) unsigned char RAW[25216];
  unsigned short* Vw = (unsigned short*)(RAW + wave * (32 * VSTR * 2));
  float*          Ow = (float*)(RAW + wave * (32 * VSTR * 2));
  unsigned short* Pw = (unsigned short*)(RAW + 19456) + wave * (16 * PSTR);
  float* partM = (float*)(RAW + 24576);
  float* partL = partM + 64;
  float* rowM  = partL + 64;
  float* rowS  = rowM + 16;

  const size_t mbase = ((size_t)b * SLQ + q0) * SLK;
  const f32x4* vb4 = (const f32x4*)(V + (size_t)b * SLK * DH);

  // ---- Q A-frags from global, pre-scaled by 1/8 (exact exponent shift) ----
  const float* qp = Q + ((size_t)b * SLQ + q0 + col) * DH + quad * 8;
  bf16x8 aq0, aq1;
  {
    f32x4 a = *(const f32x4*)qp        * 0.125f;
    f32x4 c = *(const f32x4*)(qp + 4)  * 0.125f;
    f32x4 d = *(const f32x4*)(qp + 32) * 0.125f;
    f32x4 e = *(const f32x4*)(qp + 36) * 0.125f;
    aq0 = cvt8(a, c);
    aq1 = cvt8(d, e);
  }

  // =================== Pass 1: S = (Q/8)K^T, deep-pipelined ================
  const float* kp  = K + ((size_t)b * SLK + wave * 16 + col) * DH + quad * 8;
  const int*   kmp = KM + b * SLK + wave * 16 + col;
  const int*   mkp = MSK + mbase + (size_t)(quad * 4) * SLK + wave * 16 + col;

  // prologue: K tiles 0,1 (depth-2 ping-pong)
  f32x4 krg[2][4];
#pragma unroll
  for (int t = 0; t < 2; ++t) {
    const float* kq = kp + (size_t)t * (TK * DH);
    krg[t][0] = *(const f32x4*)kq;
    krg[t][1] = *(const f32x4*)(kq + 4);
    krg[t][2] = *(const f32x4*)(kq + 32);
    krg[t][3] = *(const f32x4*)(kq + 36);
  }
  // prologue: mask tiles 0..MD-1 (depth-8 rolling window)
  int msq[MD][5];
#pragma unroll
  for (int t = 0; t < MD; ++t) {
    msq[t][0] = kmp[t * TK];
#pragma unroll
    for (int r = 0; r < 4; ++r) msq[t][r + 1] = mkp[(size_t)r * SLK + t * TK];
  }

  float sreg[NKT][4];
  unsigned mbits0 = 0u, mbits1 = 0u;   // bit (kt&7)*4+r of mbits[kt>>3]
#pragma unroll
  for (int kt = 0; kt < NKT; ++kt) {
    bf16x8 bk0 = cvt8(krg[kt & 1][0], krg[kt & 1][1]);
    bf16x8 bk1 = cvt8(krg[kt & 1][2], krg[kt & 1][3]);
    if (kt < NKT - 2) {
      const float* kq = kp + (size_t)(kt + 2) * (TK * DH);
      krg[kt & 1][0] = *(const f32x4*)kq;
      krg[kt & 1][1] = *(const f32x4*)(kq + 4);
      krg[kt & 1][2] = *(const f32x4*)(kq + 32);
      krg[kt & 1][3] = *(const f32x4*)(kq + 36);
    }
    f32x4 acc = {0.f, 0.f, 0.f, 0.f};
    acc = __builtin_amdgcn_mfma_f32_16x16x32_bf16(aq0, bk0, acc, 0, 0, 0);
    acc = __builtin_amdgcn_mfma_f32_16x16x32_bf16(aq1, bk1, acc, 0, 0, 0);
#pragma unroll
    for (int r = 0; r < 4; ++r) sreg[kt][r] = acc[r];   // raw, unmasked

    // consume mask tile kt (issued >= MD iters ago): pack to 4 bits
    {
      const int km = msq[kt & (MD - 1)][0];
      unsigned bits = 0u;
#pragma unroll
      for (int r = 0; r < 4; ++r)
        bits |= (unsigned)(km & msq[kt & (MD - 1)][r + 1] & 1) << r;
      if (kt < 8) mbits0 |= bits << ((kt & 7) * 4);
      else        mbits1 |= bits << ((kt & 7) * 4);
    }
    // refill window with tile kt+MD
    if (kt < NKT - MD) {
      msq[kt & (MD - 1)][0] = kmp[(kt + MD) * TK];
#pragma unroll
      for (int r = 0; r < 4; ++r)
        msq[kt & (MD - 1)][r + 1] = mkp[(size_t)r * SLK + (kt + MD) * TK];
    }
  }

  // prefetch V step 0 (2 tiles x this wave's 16 rows) during stats phase
  f32x4 vreg[8];
#pragma unroll
  for (int j = 0; j < 8; ++j)
    vreg[j] = vb4[(size_t)((j >> 2) * TK + wave * 16 + (j & 3) * 4 + lrow) * 16 + col];

  // ====== stats: unmasked max -> butterfly -> masked exp pass -> sum =======
  float Mw[4], Cr[4];
#pragma unroll
  for (int r = 0; r < 4; ++r) {
    float m = sreg[0][r];
#pragma unroll
    for (int kt = 1; kt < NKT; ++kt) m = fmaxf(m, sreg[kt][r]);
#pragma unroll
    for (int off = 1; off < 16; off <<= 1) m = fmaxf(m, __shfl_xor(m, off, 64));
    Mw[r] = m;
    float l = 0.f;
#pragma unroll
    for (int kt = 0; kt < NKT; ++kt) {
      float e = __expf(sreg[kt][r] - m);
      const unsigned mb = (kt < 8) ? mbits0 : mbits1;
      e = ((mb >> ((kt & 7) * 4 + r)) & 1u) ? e : 0.f;
      sreg[kt][r] = e;                 // reuse in pass 2 / epilogue: p = e*Cr
      l += e;
    }
#pragma unroll
    for (int off = 1; off < 16; off <<= 1) l += __shfl_xor(l, off, 64);
    if (col == 0) {
      partM[wave * 16 + quad * 4 + r] = m;
      partL[wave * 16 + quad * 4 + r] = l;
    }
  }
  __syncthreads();
  if (tid < TQ) {
    float M = -INFINITY, L = 0.f;
#pragma unroll
    for (int w = 0; w < 4; ++w) {
      float m_ = partM[w * 16 + tid], l_ = partL[w * 16 + tid];
      float mn = fmaxf(M, m_);
      L = L * __expf(M - mn) + l_ * __expf(m_ - mn);  // finite inputs
      M = mn;
    }
    rowM[tid] = M;
    rowS[tid] = (QM[b * SLQ + q0 + tid] && L > 0.f) ? (1.f / L) : 0.f;
  }
  __syncthreads();
#pragma unroll
  for (int r = 0; r < 4; ++r)
    Cr[r] = __expf(Mw[r] - rowM[quad * 4 + r]) * rowS[quad * 4 + r];

  // ====== Pass 2 (barrier-free): 8 steps of 2 tiles, V via private LDS =====
  f32x4 acco[4] = {{0.f,0.f,0.f,0.f},{0.f,0.f,0.f,0.f},
                   {0.f,0.f,0.f,0.f},{0.f,0.f,0.f,0.f}};
#pragma unroll
  for (int st = 0; st < 8; ++st) {
    const int kt0 = st * 2, kt1 = kt0 + 1;
    // stage V rows (32: tile kt0 then kt1) into private slice
#pragma unroll
    for (int j = 0; j < 8; ++j)
      *(u16x4*)&Vw[(j * 4 + lrow) * VSTR + lc4] = cvt4(vreg[j]);

    // p (bf16) into P transpose slice only -- global P stores in epilogue
#pragma unroll
    for (int r = 0; r < 4; ++r) {
      Pw[(quad * 4 + r) * PSTR + col]      = f2bf(sreg[kt0][r] * Cr[r]);
      Pw[(quad * 4 + r) * PSTR + 16 + col] = f2bf(sreg[kt1][r] * Cr[r]);
    }

    // prefetch next step's V
    if (st < 7) {
#pragma unroll
      for (int j = 0; j < 8; ++j)
        vreg[j] = vb4[(size_t)((st * 2 + 2 + (j >> 2)) * TK + wave * 16 + (j & 3) * 4 + lrow) * 16
                      + col];
    }

    // A = P[q=col][kk=quad*8+j]; B = V[kk=quad*8+j][d=n0*16+col]
    bf16x8 ap = __builtin_bit_cast(bf16x8, *(const u16x8*)&Pw[col * PSTR + quad * 8]);
#pragma unroll
    for (int n0 = 0; n0 < 4; ++n0) {
      u16x8 rv;
#pragma unroll
      for (int j = 0; j < 8; ++j)
        rv[j] = Vw[(quad * 8 + j) * VSTR + n0 * 16 + col];
      acco[n0] = __builtin_amdgcn_mfma_f32_16x16x32_bf16(
          ap, __builtin_bit_cast(bf16x8, rv), acco[n0], 0, 0, 0);
    }
  }

  // ====== epilogue: P store burst (64 independent stores, max MLP) =========
  float* outp = OUT_P + mbase + (size_t)(quad * 4) * SLK + wave * 16 + col;
#pragma unroll
  for (int kt = 0; kt < NKT; ++kt)
#pragma unroll
    for (int r = 0; r < 4; ++r)
      outp[(size_t)r * SLK + kt * TK] = sreg[kt][r] * Cr[r];

  // ====== final O: per-wave partial -> LDS (aliases dead V) -> reduce ======
#pragma unroll
  for (int n0 = 0; n0 < 4; ++n0)
#pragma unroll
    for (int r = 0; r < 4; ++r)
      Ow[(quad * 4 + r) * OSTR + n0 * 16 + col] = acco[n0][r];
  __syncthreads();
  {
    const int qq = tid >> 4, dd = (tid & 15) * 4;
    f32x4 s = {0.f, 0.f, 0.f, 0.f};
#pragma unroll
    for (int w = 0; w < 4; ++w) {
      const float* Os = (const float*)(RAW + w * (32 * VSTR * 2));
      s += *(const f32x4*)&Os[qq * OSTR + dd];
    }
    *(f32x4*)&OUT_AV[((size_t)b * SLQ + q0 + qq) * DH + dd] = s;
  }
}

extern "C" void kernel_launch(void* const* d_in, const int* in_sizes, int n_in,
                              void* d_out, int out_size, void* d_ws, size_t ws_size,
                              hipStream_t stream) {
  const float* q  = (const float*)d_in[0];
  const float* k  = (const float*)d_in[1];
  const float* v  = (const float*)d_in[2];
  const int*   qm = (const int*)d_in[3];
  const int*   km = (const int*)d_in[4];
  const int*   mk = (const int*)d_in[5];
  float* out_av = (float*)d_out;                          // [B,LQ,D]
  float* out_p  = out_av + (size_t)NB * SLQ * DH;         // [B,LQ,LK]
  sdpa_fused<<<dim3(NB * (SLQ / TQ)), dim3(256), 0, stream>>>(q, k, v, qm, km, mk, out_av, out_p);
}

// Round 5
// 609.523 us; speedup vs baseline: 1.0012x; 1.0012x over previous
//
#include <hip/hip_runtime.h>
#include <hip/hip_bf16.h>

// Fused masked SDPA: B=64, LQ=LK=1024, D=64, temperature=8.
// R8: GUARANTEED-depth mask pipeline. R7's register-level depth-8 prefetch
// was a no-op (VGPR_Count=84 -> compiler demoted it; ~1 load in flight per
// wave explains the 1.7 TB/s plateau). Fix: masks stream through
// __builtin_amdgcn_global_load_lds into a wave-private 4-tile LDS ring
// (zero VGPR per outstanding load) with inline-asm COUNTED s_waitcnt
// vmcnt(N) -- never 0 in the loop -- so 3-4 mask tiles + 2 K tiles are in
// flight by construction. Source-order memory ops are pinned by the asm
// "memory" fences, so N per kt is exact: 24/28/32/36 (prologue ramp),
// 28 steady-state, 24/16/8 (tail).
//  - km: 16-dword prologue burst (L2/L3-hot array).
//  - consume: 4x ds_read_b32 from ring (4-way conflict, negligible) ->
//    bit-pack to 2 u32 as in R7; exp stage unchanged.
//  - sched_barrier(0) between pack and next DMA issue: scheduler can't see
//    that the DMA aliases the ds_reads' ring slot.
//  - Everything else frozen from R7 (K depth-2 regs, one-exp softmax,
//    private-LDS V transpose pass 2, epilogue P burst, plain stores).
// LDS: 25.6 KB + 16 KB ring = 41.6 KB -> still 3 blocks/CU.

#define NB   64
#define SLQ  1024
#define SLK  1024
#define DH   64
#define TQ   16
#define TK   64
#define NKT  16
#define VSTR 76   // V slice row stride (u16): 152B -> column reads 2-way max
#define PSTR 40   // P slice row stride (u16): 80B, 16B-aligned for b128
#define OSTR 68   // O partial row stride (f32)
#define MRB  25216 // mask ring base (byte offset in RAW)

typedef __attribute__((ext_vector_type(4))) float          f32x4;
typedef __attribute__((ext_vector_type(8))) __bf16         bf16x8;
typedef __attribute__((ext_vector_type(8))) unsigned short u16x8;
typedef __attribute__((ext_vector_type(4))) unsigned short u16x4;

#define WAITV(N) asm volatile("s_waitcnt vmcnt(" #N ")" ::: "memory")

static __device__ __forceinline__ void dma4(const int* g, int* l) {
  __builtin_amdgcn_global_load_lds(
      (const __attribute__((address_space(1))) void*)g,
      (__attribute__((address_space(3))) void*)l, 4, 0, 0);
}

static __device__ __forceinline__ unsigned short f2bf(float f) {
  return __builtin_bit_cast(unsigned short, (__bf16)f);   // hw cvt, RTNE
}
static __device__ __forceinline__ bf16x8 cvt8(f32x4 a, f32x4 b) {
  bf16x8 r;
#pragma unroll
  for (int i = 0; i < 4; ++i) { r[i] = (__bf16)a[i]; r[i + 4] = (__bf16)b[i]; }
  return r;
}
static __device__ __forceinline__ u16x4 cvt4(f32x4 v) {
  u16x4 h;
#pragma unroll
  for (int i = 0; i < 4; ++i) h[i] = f2bf(v[i]);
  return h;
}

__global__ __launch_bounds__(256, 3) void sdpa_fused(
    const float* __restrict__ Q, const float* __restrict__ K,
    const float* __restrict__ V, const int* __restrict__ QM,
    const int* __restrict__ KM, const int* __restrict__ MSK,
    float* __restrict__ OUT_AV, float* __restrict__ OUT_P) {
  // XCD swizzle: co-schedule same-batch blocks on one XCD for K/V L2 reuse
  const int g    = blockIdx.x;
  const int slot = g >> 3;
  const int b    = ((slot >> 6) << 3) | (g & 7);
  const int q0   = (slot & 63) * TQ;

  const int tid  = threadIdx.x;
  const int wave = tid >> 6;
  const int lane = tid & 63;
  const int col  = lane & 15;
  const int quad = lane >> 4;
  const int lrow = quad;             // staging row subgroup
  const int lc4  = col * 4;          // staging column (x4 elements)

  // LDS: [0,19456): per-wave union of V slice (4864 B) / O partial (4352 B)
  //      [19456,24576): per-wave P slice (1280 B)
  //      [24576,25216): softmax stats
  //      [25216,41600): mask ring, 4 waves x 4 tiles x 1024 B
  __shared__ __align__(16) unsigned char RAW[41600];
  unsigned short* Vw = (unsigned short*)(RAW + wave * (32 * VSTR * 2));
  float*          Ow = (float*)(RAW + wave * (32 * VSTR * 2));
  unsigned short* Pw = (unsigned short*)(RAW + 19456) + wave * (16 * PSTR);
  float* partM = (float*)(RAW + 24576);
  float* partL = partM + 64;
  float* rowM  = partL + 64;
  float* rowS  = rowM + 16;
  int*   mring = (int*)(RAW + MRB + wave * 4096);   // 4 slots x 256 ints

  const size_t mbase = ((size_t)b * SLQ + q0) * SLK;
  const f32x4* vb4 = (const f32x4*)(V + (size_t)b * SLK * DH);

  // ---- Q A-frags from global, pre-scaled by 1/8 (exact exponent shift) ----
  const float* qp = Q + ((size_t)b * SLQ + q0 + col) * DH + quad * 8;
  bf16x8 aq0, aq1;
  {
    f32x4 a = *(const f32x4*)qp        * 0.125f;
    f32x4 c = *(const f32x4*)(qp + 4)  * 0.125f;
    f32x4 d = *(const f32x4*)(qp + 32) * 0.125f;
    f32x4 e = *(const f32x4*)(qp + 36) * 0.125f;
    aq0 = cvt8(a, c);
    aq1 = cvt8(d, e);
  }

  // ---- km burst: this lane's key_mask for all 16 tiles (L2/L3-hot) -------
  const int* kmp = KM + b * SLK + wave * 16 + col;
  int kmr[NKT];
#pragma unroll
  for (int kt = 0; kt < NKT; ++kt) kmr[kt] = kmp[kt * TK];

  // ---- mask DMA prologue: tiles 0..3 into the ring (4 instr/tile) --------
  // lane l of instr i loads MSK[row = i*4 + (l>>4)][key = kt*64+wave*16+(l&15)]
  // -> LDS word i*64+l (linear), i.e. ring word = row*16 + col.
  const int* msrc = MSK + mbase + (size_t)(lane >> 4) * SLK + wave * 16 + (lane & 15);
#pragma unroll
  for (int t = 0; t < 4; ++t)
#pragma unroll
    for (int i = 0; i < 4; ++i)
      dma4(msrc + (size_t)i * 4 * SLK + t * TK, mring + t * 256 + i * 64);

  // =================== Pass 1: S = (Q/8)K^T, counted-vmcnt pipeline ========
  const float* kp = K + ((size_t)b * SLK + wave * 16 + col) * DH + quad * 8;

  // K prologue: tiles 0,1 (depth-2 ping-pong)
  f32x4 krg[2][4];
#pragma unroll
  for (int t = 0; t < 2; ++t) {
    const float* kq = kp + (size_t)t * (TK * DH);
    krg[t][0] = *(const f32x4*)kq;
    krg[t][1] = *(const f32x4*)(kq + 4);
    krg[t][2] = *(const f32x4*)(kq + 32);
    krg[t][3] = *(const f32x4*)(kq + 36);
  }

  float sreg[NKT][4];
  unsigned mbits0 = 0u, mbits1 = 0u;   // bit (kt&7)*4+r of mbits[kt>>3]
#pragma unroll
  for (int kt = 0; kt < NKT; ++kt) {
    bf16x8 bk0 = cvt8(krg[kt & 1][0], krg[kt & 1][1]);
    bf16x8 bk1 = cvt8(krg[kt & 1][2], krg[kt & 1][3]);
    if (kt < NKT - 2) {
      const float* kq = kp + (size_t)(kt + 2) * (TK * DH);
      krg[kt & 1][0] = *(const f32x4*)kq;
      krg[kt & 1][1] = *(const f32x4*)(kq + 4);
      krg[kt & 1][2] = *(const f32x4*)(kq + 32);
      krg[kt & 1][3] = *(const f32x4*)(kq + 36);
    }
    f32x4 acc = {0.f, 0.f, 0.f, 0.f};
    acc = __builtin_amdgcn_mfma_f32_16x16x32_bf16(aq0, bk0, acc, 0, 0, 0);
    acc = __builtin_amdgcn_mfma_f32_16x16x32_bf16(aq1, bk1, acc, 0, 0, 0);
#pragma unroll
    for (int r = 0; r < 4; ++r) sreg[kt][r] = acc[r];   // raw, unmasked

    // counted wait: >=N newer VMEM ops were issued after mask tile kt's DMA
    if      (kt == 0)  WAITV(24);
    else if (kt == 1)  WAITV(28);
    else if (kt == 2)  WAITV(32);
    else if (kt == 3)  WAITV(36);
    else if (kt <= 12) WAITV(28);
    else if (kt == 13) WAITV(24);
    else if (kt == 14) WAITV(16);
    else               WAITV(8);

    // consume mask tile kt from ring slot kt&3, pack to 4 bits
    {
      const int* mt = mring + (kt & 3) * 256;
      unsigned bits = 0u;
#pragma unroll
      for (int r = 0; r < 4; ++r)
        bits |= (unsigned)(kmr[kt] & mt[(quad * 4 + r) * 16 + col] & 1) << r;
      if (kt < 8) mbits0 |= bits << ((kt & 7) * 4);
      else        mbits1 |= bits << ((kt & 7) * 4);
    }
    // ring slot is now free; refill with tile kt+4 (after a hard sched
    // fence: the scheduler can't see that the DMA aliases the reads above)
    __builtin_amdgcn_sched_barrier(0);
    if (kt < NKT - 4) {
#pragma unroll
      for (int i = 0; i < 4; ++i)
        dma4(msrc + (size_t)i * 4 * SLK + (kt + 4) * TK,
             mring + (kt & 3) * 256 + i * 64);
    }
  }

  // prefetch V step 0 (2 tiles x this wave's 16 rows) during stats phase
  f32x4 vreg[8];
#pragma unroll
  for (int j = 0; j < 8; ++j)
    vreg[j] = vb4[(size_t)((j >> 2) * TK + wave * 16 + (j & 3) * 4 + lrow) * 16 + col];

  // ====== stats: unmasked max -> butterfly -> masked exp pass -> sum =======
  float Mw[4], Cr[4];
#pragma unroll
  for (int r = 0; r < 4; ++r) {
    float m = sreg[0][r];
#pragma unroll
    for (int kt = 1; kt < NKT; ++kt) m = fmaxf(m, sreg[kt][r]);
#pragma unroll
    for (int off = 1; off < 16; off <<= 1) m = fmaxf(m, __shfl_xor(m, off, 64));
    Mw[r] = m;
    float l = 0.f;
#pragma unroll
    for (int kt = 0; kt < NKT; ++kt) {
      float e = __expf(sreg[kt][r] - m);
      const unsigned mb = (kt < 8) ? mbits0 : mbits1;
      e = ((mb >> ((kt & 7) * 4 + r)) & 1u) ? e : 0.f;
      sreg[kt][r] = e;                 // reuse in pass 2 / epilogue: p = e*Cr
      l += e;
    }
#pragma unroll
    for (int off = 1; off < 16; off <<= 1) l += __shfl_xor(l, off, 64);
    if (col == 0) {
      partM[wave * 16 + quad * 4 + r] = m;
      partL[wave * 16 + quad * 4 + r] = l;
    }
  }
  __syncthreads();
  if (tid < TQ) {
    float M = -INFINITY, L = 0.f;
#pragma unroll
    for (int w = 0; w < 4; ++w) {
      float m_ = partM[w * 16 + tid], l_ = partL[w * 16 + tid];
      float mn = fmaxf(M, m_);
      L = L * __expf(M - mn) + l_ * __expf(m_ - mn);  // finite inputs
      M = mn;
    }
    rowM[tid] = M;
    rowS[tid] = (QM[b * SLQ + q0 + tid] && L > 0.f) ? (1.f / L) : 0.f;
  }
  __syncthreads();
#pragma unroll
  for (int r = 0; r < 4; ++r)
    Cr[r] = __expf(Mw[r] - rowM[quad * 4 + r]) * rowS[quad * 4 + r];

  // ====== Pass 2 (barrier-free): 8 steps of 2 tiles, V via private LDS =====
  f32x4 acco[4] = {{0.f,0.f,0.f,0.f},{0.f,0.f,0.f,0.f},
                   {0.f,0.f,0.f,0.f},{0.f,0.f,0.f,0.f}};
#pragma unroll
  for (int st = 0; st < 8; ++st) {
    const int kt0 = st * 2, kt1 = kt0 + 1;
    // stage V rows (32: tile kt0 then kt1) into private slice
#pragma unroll
    for (int j = 0; j < 8; ++j)
      *(u16x4*)&Vw[(j * 4 + lrow) * VSTR + lc4] = cvt4(vreg[j]);

    // p (bf16) into P transpose slice only -- global P stores in epilogue
#pragma unroll
    for (int r = 0; r < 4; ++r) {
      Pw[(quad * 4 + r) * PSTR + col]      = f2bf(sreg[kt0][r] * Cr[r]);
      Pw[(quad * 4 + r) * PSTR + 16 + col] = f2bf(sreg[kt1][r] * Cr[r]);
    }

    // prefetch next step's V
    if (st < 7) {
#pragma unroll
      for (int j = 0; j < 8; ++j)
        vreg[j] = vb4[(size_t)((st * 2 + 2 + (j >> 2)) * TK + wave * 16 + (j & 3) * 4 + lrow) * 16
                      + col];
    }

    // A = P[q=col][kk=quad*8+j]; B = V[kk=quad*8+j][d=n0*16+col]
    bf16x8 ap = __builtin_bit_cast(bf16x8, *(const u16x8*)&Pw[col * PSTR + quad * 8]);
#pragma unroll
    for (int n0 = 0; n0 < 4; ++n0) {
      u16x8 rv;
#pragma unroll
      for (int j = 0; j < 8; ++j)
        rv[j] = Vw[(quad * 8 + j) * VSTR + n0 * 16 + col];
      acco[n0] = __builtin_amdgcn_mfma_f32_16x16x32_bf16(
          ap, __builtin_bit_cast(bf16x8, rv), acco[n0], 0, 0, 0);
    }
  }

  // ====== epilogue: P store burst (64 independent stores, max MLP) =========
  float* outp = OUT_P + mbase + (size_t)(quad * 4) * SLK + wave * 16 + col;
#pragma unroll
  for (int kt = 0; kt < NKT; ++kt)
#pragma unroll
    for (int r = 0; r < 4; ++r)
      outp[(size_t)r * SLK + kt * TK] = sreg[kt][r] * Cr[r];

  // ====== final O: per-wave partial -> LDS (aliases dead V) -> reduce ======
#pragma unroll
  for (int n0 = 0; n0 < 4; ++n0)
#pragma unroll
    for (int r = 0; r < 4; ++r)
      Ow[(quad * 4 + r) * OSTR + n0 * 16 + col] = acco[n0][r];
  __syncthreads();
  {
    const int qq = tid >> 4, dd = (tid & 15) * 4;
    f32x4 s = {0.f, 0.f, 0.f, 0.f};
#pragma unroll
    for (int w = 0; w < 4; ++w) {
      const float* Os = (const float*)(RAW + w * (32 * VSTR * 2));
      s += *(const f32x4*)&Os[qq * OSTR + dd];
    }
    *(f32x4*)&OUT_AV[((size_t)b * SLQ + q0 + qq) * DH + dd] = s;
  }
}

extern "C" void kernel_launch(void* const* d_in, const int* in_sizes, int n_in,
                              void* d_out, int out_size, void* d_ws, size_t ws_size,
                              hipStream_t stream) {
  const float* q  = (const float*)d_in[0];
  const float* k  = (const float*)d_in[1];
  const float* v  = (const float*)d_in[2];
  const int*   qm = (const int*)d_in[3];
  const int*   km = (const int*)d_in[4];
  const int*   mk = (const int*)d_in[5];
  float* out_av = (float*)d_out;                          // [B,LQ,D]
  float* out_p  = out_av + (size_t)NB * SLQ * DH;         // [B,LQ,LK]
  sdpa_fused<<<dim3(NB * (SLQ / TQ)), dim3(256), 0, stream>>>(q, k, v, qm, km, mk, out_av, out_p);
}